// Round 1
// baseline (716.721 us; speedup 1.0000x reference)
//
#include <hip/hip_runtime.h>

typedef unsigned short u16;
typedef unsigned int u32;
typedef __attribute__((ext_vector_type(8))) short s8v;
typedef __attribute__((ext_vector_type(4))) float f4v;

#define NATOMS 200000
#define NBONDS 400000

// ---------- bf16 helpers ----------
__device__ __forceinline__ float b2f(u32 u) {
    union { u32 i; float f; } v; v.i = u << 16; return v.f;
}
__device__ __forceinline__ u16 f2b(float f) {
    union { float f; u32 i; } v; v.f = f;
    u32 r = v.i + 0x7fffu + ((v.i >> 16) & 1u);
    return (u16)(r >> 16);
}
__device__ __forceinline__ void unpack8(uint4 u, float* f) {
    f[0] = b2f(u.x & 0xffffu); f[1] = b2f(u.x >> 16);
    f[2] = b2f(u.y & 0xffffu); f[3] = b2f(u.y >> 16);
    f[4] = b2f(u.z & 0xffffu); f[5] = b2f(u.z >> 16);
    f[6] = b2f(u.w & 0xffffu); f[7] = b2f(u.w >> 16);
}
__device__ __forceinline__ uint4 pack8(const float* f) {
    uint4 o;
    o.x = (u32)f2b(f[0]) | ((u32)f2b(f[1]) << 16);
    o.y = (u32)f2b(f[2]) | ((u32)f2b(f[3]) << 16);
    o.z = (u32)f2b(f[4]) | ((u32)f2b(f[5]) << 16);
    o.w = (u32)f2b(f[6]) | ((u32)f2b(f[7]) << 16);
    return o;
}

// ---------- weight prep: k-sliced bf16 B-operand layouts ----------
// wallw: [10][768][32]  (K=320 pad of 293), n = branch*256 + head*128 + h
// wow:   [8][128][32]   (K=256)
// wiw:   [5][128][32]   (K=160 pad of 151)
__global__ void k_wprep(const float* __restrict__ Whq, const float* __restrict__ Whk,
                        const float* __restrict__ Whv, const float* __restrict__ Wo,
                        const float* __restrict__ Wi,
                        u16* __restrict__ wallw, u16* __restrict__ wow, u16* __restrict__ wiw) {
    int t = blockIdx.x * 256 + threadIdx.x;
    if (t < 245760) {
        int ks = t / 24576, rem = t % 24576;
        int n = rem >> 5, kk = rem & 31;
        int k = ks * 32 + kk;
        int branch = n >> 8, eh = n & 255;
        int e = eh >> 7, h = eh & 127;
        const float* Wp = (branch == 0) ? Whq : ((branch == 1) ? Whk : Whv);
        float v = (k < 293) ? Wp[(e * 293 + k) * 128 + h] : 0.f;
        wallw[t] = f2b(v);
    } else if (t < 278528) {
        int u = t - 245760;
        int ks = u >> 12, n = (u >> 5) & 127, kk = u & 31;
        int k = ks * 32 + kk;
        wow[u] = f2b(Wo[k * 128 + n]);
    } else if (t < 299008) {
        int u = t - 278528;
        int ks = u >> 12, n = (u >> 5) & 127, kk = u & 31;
        int k = ks * 32 + kk;
        wiw[u] = (k < 151) ? f2b(Wi[k * 128 + n]) : (u16)0;
    }
}

// ---------- h0 = LN(relu(f_atoms @ W_i + b_i)) -> bf16 ----------
// 64 atoms/block, 256 threads (4 waves), MFMA 16x16x32, K=160 (pad 151)
#define H0_SMEM (64 * 168 * 2 + 64 * 132 * 4)  // A tile + f32 out tile = 55296
__global__ __launch_bounds__(256) void k_h0(
    const float* __restrict__ fa, const u16* __restrict__ wiw,
    const float* __restrict__ bi, const float* __restrict__ g1, const float* __restrict__ b1,
    u16* __restrict__ h0w) {
    extern __shared__ char smem[];
    u16* la = (u16*)smem;                 // [64][168] bf16 (stride padded for banks)
    float* lo = (float*)(smem + 21504);   // [64][132] f32
    const int tid = threadIdx.x;
    const size_t abase = (size_t)blockIdx.x * 64;

    for (int i = tid; i < 64 * 151; i += 256) {
        int r = i / 151, c = i - r * 151;
        la[r * 168 + c] = f2b(fa[(abase + r) * 151 + c]);
    }
    for (int i = tid; i < 64 * 17; i += 256) {
        int r = i / 17, c = i - r * 17;
        la[r * 168 + 151 + c] = 0;
    }
    __syncthreads();

    const int w = tid >> 6, l = tid & 63;
    const int r16 = l & 15, kq = l >> 4;
    f4v acc[4][2];
    #pragma unroll
    for (int m = 0; m < 4; m++)
        #pragma unroll
        for (int c = 0; c < 2; c++)
            #pragma unroll
            for (int v = 0; v < 4; v++) acc[m][c][v] = 0.f;

    #pragma unroll
    for (int ks = 0; ks < 5; ++ks) {
        s8v af[4];
        #pragma unroll
        for (int m = 0; m < 4; m++)
            af[m] = *(const s8v*)&la[(m * 16 + r16) * 168 + ks * 32 + kq * 8];
        #pragma unroll
        for (int c = 0; c < 2; c++) {
            int n = w * 32 + c * 16 + r16;
            s8v bf = *(const s8v*)&wiw[ks * 4096 + n * 32 + kq * 8];
            #pragma unroll
            for (int m = 0; m < 4; m++)
                acc[m][c] = __builtin_amdgcn_mfma_f32_16x16x32_bf16(af[m], bf, acc[m][c], 0, 0, 0);
        }
    }
    #pragma unroll
    for (int c = 0; c < 2; c++) {
        int col = w * 32 + c * 16 + r16;
        float bias = bi[col];
        #pragma unroll
        for (int m = 0; m < 4; m++) {
            #pragma unroll
            for (int v = 0; v < 4; v++) {
                int row = m * 16 + kq * 4 + v;
                lo[row * 132 + col] = fmaxf(acc[m][c][v] + bias, 0.f);
            }
        }
    }
    __syncthreads();

    // LayerNorm: 4 lanes per atom
    const int ga = tid >> 2, sb = tid & 3;
    float vals[32], s = 0.f, s2 = 0.f;
    #pragma unroll
    for (int j = 0; j < 32; j++) {
        float v = lo[ga * 132 + sb + 4 * j];
        vals[j] = v; s += v; s2 += v * v;
    }
    s += __shfl_xor(s, 1); s += __shfl_xor(s, 2);
    s2 += __shfl_xor(s2, 1); s2 += __shfl_xor(s2, 2);
    float mu = s * (1.f / 128.f), var = s2 * (1.f / 128.f) - mu * mu;
    float rs = rsqrtf(var + 1e-5f);
    u16* orow = h0w + (abase + ga) * 128;
    #pragma unroll
    for (int j = 0; j < 32; j++) {
        int col = sb + 4 * j;
        orow[col] = f2b(g1[col] * (vals[j] - mu) * rs + b1[col]);
    }
}

// ---------- msg (h0 part): msg[:,0:128] = sum_j h0[a2a[n,j]]; zeros 296..319 ----------
__global__ void k_msg_h0(const u16* __restrict__ h0w, const int* __restrict__ a2a,
                         u16* __restrict__ msgw) {
    int t = blockIdx.x * 256 + threadIdx.x;
    if (t >= NATOMS * 19) return;
    u32 atom = (u32)t / 19u, c = (u32)t % 19u;
    if (c < 16) {
        const int* na = a2a + (size_t)atom * 6;
        float a[8] = {0, 0, 0, 0, 0, 0, 0, 0};
        #pragma unroll
        for (int j = 0; j < 6; j++) {
            uint4 u = *(const uint4*)&h0w[(size_t)(u32)na[j] * 128 + c * 8];
            a[0] += b2f(u.x & 0xffffu); a[1] += b2f(u.x >> 16);
            a[2] += b2f(u.y & 0xffffu); a[3] += b2f(u.y >> 16);
            a[4] += b2f(u.z & 0xffffu); a[5] += b2f(u.z >> 16);
            a[6] += b2f(u.w & 0xffffu); a[7] += b2f(u.w >> 16);
        }
        *(uint4*)&msgw[(size_t)atom * 320 + c * 8] = pack8(a);
    } else {
        uint4 z = {0, 0, 0, 0};
        *(uint4*)&msgw[(size_t)atom * 320 + 296 + (c - 16) * 8] = z;
    }
}

// ---------- msg (bond part): msg[:,128:296] = sum_j f_bonds[a2b[n,j]] (165 cols + 3 zeros) ----------
__global__ void k_msg_bond(const float* __restrict__ fb, const int* __restrict__ a2b,
                           u16* __restrict__ msgw) {
    int t = blockIdx.x * 256 + threadIdx.x;
    if (t >= NATOMS * 21) return;
    u32 atom = (u32)t / 21u, c = (u32)t % 21u;
    const int* nb = a2b + (size_t)atom * 6;
    float a[8] = {0, 0, 0, 0, 0, 0, 0, 0};
    #pragma unroll
    for (int j = 0; j < 6; j++) {
        const float* src = fb + (size_t)(u32)nb[j] * 165 + c * 8;
        #pragma unroll
        for (int q = 0; q < 8; q++) {
            if ((int)(c * 8 + q) < 165) a[q] += src[q];
        }
    }
    *(uint4*)&msgw[(size_t)atom * 320 + 128 + c * 8] = pack8(a);
}

// ---------- fused: QKV proj + attention + W_o + LN2 + residual ----------
// 64 atoms/block, 512 threads (8 waves). LDS regions (byte offsets):
//   lh0  [0,16384)            h0 tile, live whole kernel
//   lmsg [16384,58368)        [64][328] bf16   (GEMM phase)
//   lwtb [58368,107520)       [768][64B] swizzled W tile (GEMM phase)
//   lqkv [16384,115712)       [64][776] bf16   (post-GEMM, overlaps msg+wt)
//   lx   [115712,149504)      [64][264] bf16
//   lxo  [16384,50176)        [64][132] f32    (overlaps dead lqkv)
#define SMEM_FUSED 149504
__global__ __launch_bounds__(512, 2) void k_fused(
    const u16* __restrict__ msgw, const u16* __restrict__ h0w,
    const u16* __restrict__ wallw, const u16* __restrict__ wow,
    const float* __restrict__ bhq, const float* __restrict__ bhk, const float* __restrict__ bhv,
    const float* __restrict__ bo, const float* __restrict__ g2, const float* __restrict__ b2,
    float* __restrict__ out) {
    extern __shared__ char smem[];
    u16* lh0 = (u16*)smem;
    u16* lmsg = (u16*)(smem + 16384);
    char* lwtb = smem + 58368;
    u16* lqkv = (u16*)(smem + 16384);
    u16* lx = (u16*)(smem + 115712);
    float* lxo = (float*)(smem + 16384);

    const int tid = threadIdx.x;
    const size_t abase = (size_t)blockIdx.x * 64;

    // stage h0 tile [64][128]
    #pragma unroll
    for (int ii = 0; ii < 2; ++ii) {
        int i = tid + ii * 512;
        int r = i >> 4, c = (i & 15) << 3;
        *(uint4*)&lh0[r * 128 + c] = *(const uint4*)&h0w[(abase + r) * 128 + c];
    }
    // stage msg tile [64][320] -> LDS stride 328
    #pragma unroll
    for (int ii = 0; ii < 5; ++ii) {
        int i = tid + ii * 512;
        int r = i / 40, c = (i - r * 40) << 3;
        *(uint4*)&lmsg[r * 328 + c] = *(const uint4*)&msgw[(abase + r) * 320 + c];
    }

    const int w = tid >> 6, l = tid & 63;
    const int r16 = l & 15, kq = l >> 4;

    f4v acc[4][6];
    #pragma unroll
    for (int m = 0; m < 4; m++)
        #pragma unroll
        for (int c = 0; c < 6; c++)
            #pragma unroll
            for (int v = 0; v < 4; v++) acc[m][c][v] = 0.f;

    for (int ks = 0; ks < 10; ++ks) {
        __syncthreads();   // prev frag reads done (and initial stage on ks==0)
        const u16* wsrc = wallw + ks * 24576;
        #pragma unroll
        for (int ii = 0; ii < 6; ++ii) {
            int i = tid + ii * 512;
            int n = i >> 2, kc = i & 3;
            *(uint4*)(lwtb + n * 64 + ((kc ^ (n & 3)) << 4)) = *(const uint4*)&wsrc[n * 32 + (kc << 3)];
        }
        __syncthreads();
        s8v af[4];
        #pragma unroll
        for (int m = 0; m < 4; m++)
            af[m] = *(const s8v*)&lmsg[(m * 16 + r16) * 328 + ks * 32 + kq * 8];
        s8v bf[6];
        #pragma unroll
        for (int c = 0; c < 6; c++) {
            int n = w * 96 + c * 16 + r16;
            bf[c] = *(const s8v*)(lwtb + n * 64 + ((kq ^ (n & 3)) << 4));
        }
        #pragma unroll
        for (int m = 0; m < 4; m++)
            #pragma unroll
            for (int c = 0; c < 6; c++)
                acc[m][c] = __builtin_amdgcn_mfma_f32_16x16x32_bf16(af[m], bf[c], acc[m][c], 0, 0, 0);
    }
    __syncthreads();

    // QKV = relu(h0 + proj + bias) -> lqkv bf16
    #pragma unroll
    for (int c = 0; c < 6; c++) {
        int col = w * 96 + c * 16 + r16;
        const float* bptr = (col < 256) ? bhq : ((col < 512) ? bhk : bhv);
        float bias = bptr[col & 255];
        #pragma unroll
        for (int m = 0; m < 4; m++) {
            #pragma unroll
            for (int v = 0; v < 4; v++) {
                int row = m * 16 + kq * 4 + v;
                float hv = b2f(lh0[row * 128 + (col & 127)]);
                lqkv[row * 776 + col] = f2b(fmaxf(acc[m][c][v] + hv + bias, 0.f));
            }
        }
    }
    __syncthreads();

    // attention over heads (2x2), 8 lanes per atom
    {
        const int g = tid >> 3, sub = tid & 7;
        const u16* qr = lqkv + g * 776;
        float q0[16], q1[16], k0[16], k1[16];
        unpack8(*(const uint4*)&qr[sub * 16], q0);
        unpack8(*(const uint4*)&qr[sub * 16 + 8], q0 + 8);
        unpack8(*(const uint4*)&qr[128 + sub * 16], q1);
        unpack8(*(const uint4*)&qr[128 + sub * 16 + 8], q1 + 8);
        unpack8(*(const uint4*)&qr[256 + sub * 16], k0);
        unpack8(*(const uint4*)&qr[256 + sub * 16 + 8], k0 + 8);
        unpack8(*(const uint4*)&qr[384 + sub * 16], k1);
        unpack8(*(const uint4*)&qr[384 + sub * 16 + 8], k1 + 8);
        float s00 = 0, s01 = 0, s10 = 0, s11 = 0;
        #pragma unroll
        for (int j = 0; j < 16; j++) {
            s00 = fmaf(q0[j], k0[j], s00); s01 = fmaf(q0[j], k1[j], s01);
            s10 = fmaf(q1[j], k0[j], s10); s11 = fmaf(q1[j], k1[j], s11);
        }
        #pragma unroll
        for (int m = 1; m < 8; m <<= 1) {
            s00 += __shfl_xor(s00, m); s01 += __shfl_xor(s01, m);
            s10 += __shfl_xor(s10, m); s11 += __shfl_xor(s11, m);
        }
        const float sc = 0.08838834764831845f;  // 1/sqrt(128)
        s00 *= sc; s01 *= sc; s10 *= sc; s11 *= sc;
        float m0 = fmaxf(s00, s01), e00 = __expf(s00 - m0), e01 = __expf(s01 - m0);
        float i0 = 1.f / (e00 + e01), a00 = e00 * i0, a01 = e01 * i0;
        float m1 = fmaxf(s10, s11), e10 = __expf(s10 - m1), e11 = __expf(s11 - m1);
        float i1 = 1.f / (e10 + e11), a10 = e10 * i1, a11 = e11 * i1;
        float v0[16], v1[16], x0[16], x1[16];
        unpack8(*(const uint4*)&qr[512 + sub * 16], v0);
        unpack8(*(const uint4*)&qr[512 + sub * 16 + 8], v0 + 8);
        unpack8(*(const uint4*)&qr[640 + sub * 16], v1);
        unpack8(*(const uint4*)&qr[640 + sub * 16 + 8], v1 + 8);
        #pragma unroll
        for (int j = 0; j < 16; j++) {
            x0[j] = a00 * v0[j] + a01 * v1[j];
            x1[j] = a10 * v0[j] + a11 * v1[j];
        }
        *(uint4*)&lx[g * 264 + sub * 16] = pack8(x0);
        *(uint4*)&lx[g * 264 + sub * 16 + 8] = pack8(x0 + 8);
        *(uint4*)&lx[g * 264 + 128 + sub * 16] = pack8(x1);
        *(uint4*)&lx[g * 264 + 128 + sub * 16 + 8] = pack8(x1 + 8);
    }
    __syncthreads();

    // x @ W_o  (K=256), B frags straight from L2-resident wow
    {
        const int mb = w >> 1, ch = w & 1;
        f4v oa[4];
        #pragma unroll
        for (int c = 0; c < 4; c++)
            #pragma unroll
            for (int v = 0; v < 4; v++) oa[c][v] = 0.f;
        #pragma unroll
        for (int ks = 0; ks < 8; ++ks) {
            s8v a = *(const s8v*)&lx[(mb * 16 + r16) * 264 + ks * 32 + kq * 8];
            #pragma unroll
            for (int c = 0; c < 4; c++) {
                int n = ch * 64 + c * 16 + r16;
                s8v b = *(const s8v*)&wow[ks * 4096 + n * 32 + kq * 8];
                oa[c] = __builtin_amdgcn_mfma_f32_16x16x32_bf16(a, b, oa[c], 0, 0, 0);
            }
        }
        #pragma unroll
        for (int c = 0; c < 4; c++) {
            int col = ch * 64 + c * 16 + r16;
            #pragma unroll
            for (int v = 0; v < 4; v++) {
                int row = mb * 16 + kq * 4 + v;
                lxo[row * 132 + col] = oa[c][v];
            }
        }
    }
    __syncthreads();

    // out = h0 + LN(x_out + b_o)
    {
        const int ga = tid >> 3, sb = tid & 7;
        float vals[16], s = 0.f, s2 = 0.f;
        #pragma unroll
        for (int j = 0; j < 16; j++) {
            int col = sb + 8 * j;
            float v = lxo[ga * 132 + col] + bo[col];
            vals[j] = v; s += v; s2 += v * v;
        }
        #pragma unroll
        for (int m = 1; m < 8; m <<= 1) { s += __shfl_xor(s, m); s2 += __shfl_xor(s2, m); }
        float mu = s * (1.f / 128.f), var = s2 * (1.f / 128.f) - mu * mu;
        float rs = rsqrtf(var + 1e-5f);
        float* orow = out + (abase + ga) * 128;
        #pragma unroll
        for (int j = 0; j < 16; j++) {
            int col = sb + 8 * j;
            orow[col] = g2[col] * (vals[j] - mu) * rs + b2[col] + b2f(lh0[ga * 128 + col]);
        }
    }
}

extern "C" void kernel_launch(void* const* d_in, const int* in_sizes, int n_in,
                              void* d_out, int out_size, void* d_ws, size_t ws_size,
                              hipStream_t stream) {
    const float* f_atoms = (const float*)d_in[0];
    const float* f_bonds = (const float*)d_in[1];
    const int* a2a = (const int*)d_in[2];
    const int* a2b = (const int*)d_in[3];
    const float* W_i = (const float*)d_in[4];
    const float* b_i = (const float*)d_in[5];
    const float* ln1g = (const float*)d_in[6];
    const float* ln1b = (const float*)d_in[7];
    const float* Whq = (const float*)d_in[8];
    const float* bhq = (const float*)d_in[9];
    const float* Whk = (const float*)d_in[10];
    const float* bhk = (const float*)d_in[11];
    const float* Whv = (const float*)d_in[12];
    const float* bhv = (const float*)d_in[13];
    const float* Wo = (const float*)d_in[14];
    const float* bo = (const float*)d_in[15];
    const float* ln2g = (const float*)d_in[16];
    const float* ln2b = (const float*)d_in[17];
    float* out = (float*)d_out;

    char* ws = (char*)d_ws;
    u16* h0w = (u16*)(ws + 0);                 //  51,200,000 B
    u16* msgw = (u16*)(ws + 51200000);         // 128,000,000 B
    u16* wallw = (u16*)(ws + 179200000);       //     491,520 B
    u16* wow = (u16*)(ws + 179691520);         //      65,536 B
    u16* wiw = (u16*)(ws + 179757056);         //      40,960 B  (total ~179.8 MB)

    hipFuncSetAttribute(reinterpret_cast<const void*>(k_fused),
                        hipFuncAttributeMaxDynamicSharedMemorySize, SMEM_FUSED);

    k_wprep<<<1168, 256, 0, stream>>>(Whq, Whk, Whv, Wo, W_i, wallw, wow, wiw);
    k_h0<<<3125, 256, H0_SMEM, stream>>>(f_atoms, wiw, b_i, ln1g, ln1b, h0w);
    k_msg_h0<<<14844, 256, 0, stream>>>(h0w, a2a, msgw);
    k_msg_bond<<<16407, 256, 0, stream>>>(f_bonds, a2b, msgw);
    k_fused<<<3125, 512, SMEM_FUSED, stream>>>(msgw, h0w, wallw, wow,
                                               bhq, bhk, bhv, bo, ln2g, ln2b, out);
}

// Round 2
// 703.317 us; speedup vs baseline: 1.0191x; 1.0191x over previous
//
#include <hip/hip_runtime.h>

typedef unsigned short u16;
typedef unsigned int u32;
typedef __attribute__((ext_vector_type(8))) short s8v;
typedef __attribute__((ext_vector_type(4))) float f4v;

#define NATOMS 200000
#define NBONDS 400000

// ---------- bf16 helpers ----------
__device__ __forceinline__ float b2f(u32 u) {
    union { u32 i; float f; } v; v.i = u << 16; return v.f;
}
__device__ __forceinline__ u16 f2b(float f) {
    union { float f; u32 i; } v; v.f = f;
    u32 r = v.i + 0x7fffu + ((v.i >> 16) & 1u);
    return (u16)(r >> 16);
}
__device__ __forceinline__ uint4 pack8(const float* f) {
    uint4 o;
    o.x = (u32)f2b(f[0]) | ((u32)f2b(f[1]) << 16);
    o.y = (u32)f2b(f[2]) | ((u32)f2b(f[3]) << 16);
    o.z = (u32)f2b(f[4]) | ((u32)f2b(f[5]) << 16);
    o.w = (u32)f2b(f[6]) | ((u32)f2b(f[7]) << 16);
    return o;
}

// ---------- weight prep ----------
// wallw: [10 ks][768 n'][32 kk]; n' = (h>>3)*48 + branch*16 + head*8 + (h&7)
//   so wave w (=h>>3) frag c (=branch) covers r16 = head*8+(h&7), h = w*8+(r16&7).
// wow:   [8][128][32]   (K=256)
// wiw:   [5][128][32]   (K=160 pad of 151)
__global__ void k_wprep(const float* __restrict__ Whq, const float* __restrict__ Whk,
                        const float* __restrict__ Whv, const float* __restrict__ Wo,
                        const float* __restrict__ Wi,
                        u16* __restrict__ wallw, u16* __restrict__ wow, u16* __restrict__ wiw) {
    int t = blockIdx.x * 256 + threadIdx.x;
    if (t < 245760) {
        int ks = t / 24576, rem = t % 24576;
        int n = rem >> 5, kk = rem & 31;
        int k = ks * 32 + kk;
        int hg = n / 48, r48 = n % 48;
        int branch = r48 >> 4, r16i = r48 & 15;
        int head = r16i >> 3, h = hg * 8 + (r16i & 7);
        const float* Wp = (branch == 0) ? Whq : ((branch == 1) ? Whk : Whv);
        float val = (k < 293) ? Wp[(head * 293 + k) * 128 + h] : 0.f;
        wallw[t] = f2b(val);
    } else if (t < 278528) {
        int u = t - 245760;
        int ks = u >> 12, n = (u >> 5) & 127, kk = u & 31;
        int k = ks * 32 + kk;
        wow[u] = f2b(Wo[k * 128 + n]);
    } else if (t < 299008) {
        int u = t - 278528;
        int ks = u >> 12, n = (u >> 5) & 127, kk = u & 31;
        int k = ks * 32 + kk;
        wiw[u] = (k < 151) ? f2b(Wi[k * 128 + n]) : (u16)0;
    }
}

// ---------- h0 = LN(relu(f_atoms @ W_i + b_i)) -> bf16 ----------
#define H0_SMEM (64 * 168 * 2 + 64 * 132 * 4)
__global__ __launch_bounds__(256) void k_h0(
    const float* __restrict__ fa, const u16* __restrict__ wiw,
    const float* __restrict__ bi, const float* __restrict__ g1, const float* __restrict__ b1,
    u16* __restrict__ h0w) {
    extern __shared__ char smem[];
    u16* la = (u16*)smem;                 // [64][168]
    float* lo = (float*)(smem + 21504);   // [64][132]
    const int tid = threadIdx.x;
    const size_t abase = (size_t)blockIdx.x * 64;

    for (int i = tid; i < 64 * 151; i += 256) {
        int r = i / 151, c = i - r * 151;
        la[r * 168 + c] = f2b(fa[(abase + r) * 151 + c]);
    }
    for (int i = tid; i < 64 * 17; i += 256) {
        int r = i / 17, c = i - r * 17;
        la[r * 168 + 151 + c] = 0;
    }
    __syncthreads();

    const int w = tid >> 6, l = tid & 63;
    const int r16 = l & 15, kq = l >> 4;
    f4v acc[4][2];
    #pragma unroll
    for (int m = 0; m < 4; m++)
        #pragma unroll
        for (int c = 0; c < 2; c++)
            #pragma unroll
            for (int v = 0; v < 4; v++) acc[m][c][v] = 0.f;

    #pragma unroll
    for (int ks = 0; ks < 5; ++ks) {
        s8v af[4];
        #pragma unroll
        for (int m = 0; m < 4; m++)
            af[m] = *(const s8v*)&la[(m * 16 + r16) * 168 + ks * 32 + kq * 8];
        #pragma unroll
        for (int c = 0; c < 2; c++) {
            int n = w * 32 + c * 16 + r16;
            s8v bf = *(const s8v*)&wiw[ks * 4096 + n * 32 + kq * 8];
            #pragma unroll
            for (int m = 0; m < 4; m++)
                acc[m][c] = __builtin_amdgcn_mfma_f32_16x16x32_bf16(af[m], bf, acc[m][c], 0, 0, 0);
        }
    }
    #pragma unroll
    for (int c = 0; c < 2; c++) {
        int col = w * 32 + c * 16 + r16;
        float bias = bi[col];
        #pragma unroll
        for (int m = 0; m < 4; m++) {
            #pragma unroll
            for (int v = 0; v < 4; v++) {
                int row = m * 16 + kq * 4 + v;
                lo[row * 132 + col] = fmaxf(acc[m][c][v] + bias, 0.f);
            }
        }
    }
    __syncthreads();

    const int ga = tid >> 2, sb = tid & 3;
    float vals[32], s = 0.f, s2 = 0.f;
    #pragma unroll
    for (int j = 0; j < 32; j++) {
        float v = lo[ga * 132 + sb + 4 * j];
        vals[j] = v; s += v; s2 += v * v;
    }
    s += __shfl_xor(s, 1); s += __shfl_xor(s, 2);
    s2 += __shfl_xor(s2, 1); s2 += __shfl_xor(s2, 2);
    float mu = s * (1.f / 128.f), var = s2 * (1.f / 128.f) - mu * mu;
    float rs = rsqrtf(var + 1e-5f);
    u16* orow = h0w + (abase + ga) * 128;
    #pragma unroll
    for (int j = 0; j < 32; j++) {
        int col = sb + 4 * j;
        orow[col] = f2b(g1[col] * (vals[j] - mu) * rs + b1[col]);
    }
}

// ---------- msg (h0 part) ----------
__global__ void k_msg_h0(const u16* __restrict__ h0w, const int* __restrict__ a2a,
                         u16* __restrict__ msgw) {
    int t = blockIdx.x * 256 + threadIdx.x;
    if (t >= NATOMS * 19) return;
    u32 atom = (u32)t / 19u, c = (u32)t % 19u;
    if (c < 16) {
        const int* na = a2a + (size_t)atom * 6;
        float a[8] = {0, 0, 0, 0, 0, 0, 0, 0};
        #pragma unroll
        for (int j = 0; j < 6; j++) {
            uint4 u = *(const uint4*)&h0w[(size_t)(u32)na[j] * 128 + c * 8];
            a[0] += b2f(u.x & 0xffffu); a[1] += b2f(u.x >> 16);
            a[2] += b2f(u.y & 0xffffu); a[3] += b2f(u.y >> 16);
            a[4] += b2f(u.z & 0xffffu); a[5] += b2f(u.z >> 16);
            a[6] += b2f(u.w & 0xffffu); a[7] += b2f(u.w >> 16);
        }
        *(uint4*)&msgw[(size_t)atom * 320 + c * 8] = pack8(a);
    } else {
        uint4 z = {0, 0, 0, 0};
        *(uint4*)&msgw[(size_t)atom * 320 + 296 + (c - 16) * 8] = z;
    }
}

// ---------- msg (bond part) ----------
__global__ void k_msg_bond(const float* __restrict__ fb, const int* __restrict__ a2b,
                           u16* __restrict__ msgw) {
    int t = blockIdx.x * 256 + threadIdx.x;
    if (t >= NATOMS * 21) return;
    u32 atom = (u32)t / 21u, c = (u32)t % 21u;
    const int* nb = a2b + (size_t)atom * 6;
    float a[8] = {0, 0, 0, 0, 0, 0, 0, 0};
    #pragma unroll
    for (int j = 0; j < 6; j++) {
        const float* src = fb + (size_t)(u32)nb[j] * 165 + c * 8;
        #pragma unroll
        for (int q = 0; q < 8; q++) {
            if ((int)(c * 8 + q) < 165) a[q] += src[q];
        }
    }
    *(uint4*)&msgw[(size_t)atom * 320 + 128 + c * 8] = pack8(a);
}

// ---------- fused: QKV proj (weights from L2, no K-loop barriers) +
//            in-register attention + W_o + LN2 + residual ----------
// 64 atoms/block, 1024 threads (16 waves), 1 block/CU, 4 waves/SIMD.
// LDS: lh0[64][128]u16 @0 (16K) | lmsg[64][328]u16 @16384 (42K, GEMM1 only)
//      lx[64][264]u16 @16384 (33K, overlaps lmsg) | sco[16][64]f4 @58368 (16K)
//      attn[64][4]f32 @74752 (1K) | pp[64][8]f32 @75776 (2K)  total 77824
#define SMEM_FUSED 77824
__global__ __launch_bounds__(1024) void k_fused(
    const u16* __restrict__ msgw, const u16* __restrict__ h0w,
    const u16* __restrict__ wallw, const u16* __restrict__ wow,
    const float* __restrict__ bhq, const float* __restrict__ bhk, const float* __restrict__ bhv,
    const float* __restrict__ bo, const float* __restrict__ g2, const float* __restrict__ b2,
    float* __restrict__ out) {
    extern __shared__ char smem[];
    u16* lh0 = (u16*)smem;
    u16* lmsg = (u16*)(smem + 16384);
    u16* lx = (u16*)(smem + 16384);
    f4v* sco = (f4v*)(smem + 58368);
    float* attn = (float*)(smem + 74752);
    float* pp = (float*)(smem + 75776);

    const int tid = threadIdx.x;
    const size_t abase = (size_t)blockIdx.x * 64;
    const int w = tid >> 6, l = tid & 63;
    const int r16 = l & 15, kq = l >> 4;

    // B-frag base for QKV GEMM (per-wave cols in permuted wallw layout);
    // issue first K-step's loads BEFORE the staging barrier to hide L2 latency.
    const u16* bp = wallw + (size_t)(w * 48 + r16) * 32 + kq * 8;
    s8v bfA0 = *(const s8v*)&bp[0];
    s8v bfA1 = *(const s8v*)&bp[512];
    s8v bfA2 = *(const s8v*)&bp[1024];

    // stage lh0 [64][128]
    {
        int r = tid >> 4, c = (tid & 15) << 3;
        *(uint4*)&lh0[r * 128 + c] = *(const uint4*)&h0w[(abase + r) * 128 + c];
    }
    // stage lmsg [64][320] -> stride 328
    #pragma unroll
    for (int ii = 0; ii < 3; ++ii) {
        int i = tid + ii * 1024;
        if (i < 2560) {
            int r = i / 40, c = (i - r * 40) << 3;
            *(uint4*)&lmsg[r * 328 + c] = *(const uint4*)&msgw[(abase + r) * 320 + c];
        }
    }
    __syncthreads();

    f4v acc[4][3];
    #pragma unroll
    for (int m = 0; m < 4; m++)
        #pragma unroll
        for (int c = 0; c < 3; c++)
            #pragma unroll
            for (int v = 0; v < 4; v++) acc[m][c][v] = 0.f;

    const u16* ap = lmsg + r16 * 328 + kq * 8;
    s8v bfB0, bfB1, bfB2;

    // K-loop: 10 steps, double-buffered B frags from L2, no barriers.
    #pragma unroll
    for (int kp = 0; kp < 5; ++kp) {
        {   // even step ks=2kp uses bfA, prefetch bfB
            const int ks = 2 * kp;
            const u16* nb = bp + (size_t)(ks + 1) * 24576;
            bfB0 = *(const s8v*)&nb[0];
            bfB1 = *(const s8v*)&nb[512];
            bfB2 = *(const s8v*)&nb[1024];
            #pragma unroll
            for (int m = 0; m < 4; m++) {
                s8v af = *(const s8v*)&ap[m * 16 * 328 + ks * 32];
                acc[m][0] = __builtin_amdgcn_mfma_f32_16x16x32_bf16(af, bfA0, acc[m][0], 0, 0, 0);
                acc[m][1] = __builtin_amdgcn_mfma_f32_16x16x32_bf16(af, bfA1, acc[m][1], 0, 0, 0);
                acc[m][2] = __builtin_amdgcn_mfma_f32_16x16x32_bf16(af, bfA2, acc[m][2], 0, 0, 0);
            }
        }
        {   // odd step ks=2kp+1 uses bfB, prefetch bfA
            const int ks = 2 * kp + 1;
            if (kp < 4) {
                const u16* nb = bp + (size_t)(ks + 1) * 24576;
                bfA0 = *(const s8v*)&nb[0];
                bfA1 = *(const s8v*)&nb[512];
                bfA2 = *(const s8v*)&nb[1024];
            }
            #pragma unroll
            for (int m = 0; m < 4; m++) {
                s8v af = *(const s8v*)&ap[m * 16 * 328 + ks * 32];
                acc[m][0] = __builtin_amdgcn_mfma_f32_16x16x32_bf16(af, bfB0, acc[m][0], 0, 0, 0);
                acc[m][1] = __builtin_amdgcn_mfma_f32_16x16x32_bf16(af, bfB1, acc[m][1], 0, 0, 0);
                acc[m][2] = __builtin_amdgcn_mfma_f32_16x16x32_bf16(af, bfB2, acc[m][2], 0, 0, 0);
            }
        }
    }

    // ---- in-register attention ----
    // lane: head = r16>>3, h = w*8 + (r16&7); c=0/1/2 -> Q/K/V at (head,h)
    const int head = r16 >> 3;
    const int h = w * 8 + (r16 & 7);
    const bool up = head != 0;
    const float bq = bhq[head * 128 + h];
    const float bk = bhk[head * 128 + h];
    const float bv = bhv[head * 128 + h];

    float k0 = 0.f, k1 = 0.f, k2 = 0.f, k3 = 0.f;
    #pragma unroll
    for (int m = 0; m < 4; m++) {
        #pragma unroll
        for (int v = 0; v < 4; v++) {
            int row = m * 16 + kq * 4 + v;
            float h0v = b2f(lh0[row * 128 + h]);
            float q  = fmaxf(acc[m][0][v] + h0v + bq, 0.f);
            float kk = fmaxf(acc[m][1][v] + h0v + bk, 0.f);
            float vv = fmaxf(acc[m][2][v] + h0v + bv, 0.f);
            acc[m][2][v] = vv;  // keep relu'd V for the apply phase
            float kx = __shfl_xor(kk, 8);
            float pA = q * kk;  // lower: Q0K0 part, upper: Q1K1 part
            float pB = q * kx;  // lower: Q0K1 part, upper: Q1K0 part
            pA += __shfl_xor(pA, 1); pA += __shfl_xor(pA, 2); pA += __shfl_xor(pA, 4);
            pB += __shfl_xor(pB, 1); pB += __shfl_xor(pB, 2); pB += __shfl_xor(pB, 4);
            float pAx = __shfl_xor(pA, 8);
            float pBx = __shfl_xor(pB, 8);
            float s00 = up ? pAx : pA, s11 = up ? pA : pAx;
            float s01 = up ? pBx : pB, s10 = up ? pB : pBx;
            if (r16 == m * 4 + v) { k0 = s00; k1 = s01; k2 = s10; k3 = s11; }
        }
    }
    {
        int row = (r16 >> 2) * 16 + kq * 4 + (r16 & 3);
        f4v sv; sv[0] = k0; sv[1] = k1; sv[2] = k2; sv[3] = k3;
        sco[w * 64 + row] = sv;
    }
    __syncthreads();

    if (tid < 64) {
        f4v s = sco[tid];
        #pragma unroll
        for (int ww = 1; ww < 16; ww++) s += sco[ww * 64 + tid];
        const float sc = 0.08838834764831845f;  // 1/sqrt(128)
        float s00 = s[0] * sc, s01 = s[1] * sc, s10 = s[2] * sc, s11 = s[3] * sc;
        float m0 = fmaxf(s00, s01);
        float e00 = __expf(s00 - m0), e01 = __expf(s01 - m0);
        float i0 = 1.f / (e00 + e01);
        float m1 = fmaxf(s10, s11);
        float e10 = __expf(s10 - m1), e11 = __expf(s11 - m1);
        float i1 = 1.f / (e10 + e11);
        f4v a; a[0] = e00 * i0; a[1] = e01 * i0; a[2] = e10 * i1; a[3] = e11 * i1;
        *(f4v*)&attn[tid * 4] = a;
    }
    __syncthreads();

    // V apply -> lx[row][head*128+h] (lx overlaps dead lmsg)
    #pragma unroll
    for (int m = 0; m < 4; m++) {
        #pragma unroll
        for (int v = 0; v < 4; v++) {
            int row = m * 16 + kq * 4 + v;
            f4v a = *(f4v*)&attn[row * 4];
            float vv = acc[m][2][v];
            float vx = __shfl_xor(vv, 8);
            float x = up ? (a[2] * vx + a[3] * vv) : (a[0] * vv + a[1] * vx);
            lx[row * 264 + head * 128 + h] = f2b(x);
        }
    }
    __syncthreads();

    // ---- x @ W_o (K=256), B frags straight from L2 ----
    const int mb = w >> 2, ch = w & 3;
    f4v oa0, oa1;
    #pragma unroll
    for (int v = 0; v < 4; v++) { oa0[v] = 0.f; oa1[v] = 0.f; }
    const u16* xp = lx + (mb * 16 + r16) * 264 + kq * 8;
    const u16* wp2 = wow + (ch * 32 + r16) * 32 + kq * 8;
    #pragma unroll
    for (int ks = 0; ks < 8; ks++) {
        s8v a = *(const s8v*)&xp[ks * 32];
        s8v b0 = *(const s8v*)&wp2[ks * 4096];
        s8v b1 = *(const s8v*)&wp2[ks * 4096 + 512];
        oa0 = __builtin_amdgcn_mfma_f32_16x16x32_bf16(a, b0, oa0, 0, 0, 0);
        oa1 = __builtin_amdgcn_mfma_f32_16x16x32_bf16(a, b1, oa1, 0, 0, 0);
    }

    // ---- epilogue: LN2 via cross-wave partial sums, write out ----
    const int col0 = ch * 32 + r16, col1 = col0 + 16;
    const float bo0 = bo[col0], bo1 = bo[col1];
    float xo0[4], xo1[4], sv[4], s2v[4];
    #pragma unroll
    for (int v = 0; v < 4; v++) {
        xo0[v] = oa0[v] + bo0;
        xo1[v] = oa1[v] + bo1;
        float s = xo0[v] + xo1[v];
        float s2 = xo0[v] * xo0[v] + xo1[v] * xo1[v];
        s += __shfl_xor(s, 1); s += __shfl_xor(s, 2);
        s += __shfl_xor(s, 4); s += __shfl_xor(s, 8);
        s2 += __shfl_xor(s2, 1); s2 += __shfl_xor(s2, 2);
        s2 += __shfl_xor(s2, 4); s2 += __shfl_xor(s2, 8);
        sv[v] = s; s2v[v] = s2;
    }
    if (r16 == 0) {
        #pragma unroll
        for (int v = 0; v < 4; v++) {
            int row = mb * 16 + kq * 4 + v;
            pp[row * 8 + ch * 2] = sv[v];
            pp[row * 8 + ch * 2 + 1] = s2v[v];
        }
    }
    __syncthreads();

    const float ga0 = g2[col0], ga1 = g2[col1];
    const float bb0 = b2[col0], bb1 = b2[col1];
    #pragma unroll
    for (int v = 0; v < 4; v++) {
        int row = mb * 16 + kq * 4 + v;
        f4v p0 = *(f4v*)&pp[row * 8];
        f4v p1 = *(f4v*)&pp[row * 8 + 4];
        float ssum = p0[0] + p0[2] + p1[0] + p1[2];
        float s2sum = p0[1] + p0[3] + p1[1] + p1[3];
        float mu = ssum * (1.f / 128.f);
        float var = s2sum * (1.f / 128.f) - mu * mu;
        float rs = rsqrtf(var + 1e-5f);
        float* orow = out + (abase + row) * 128;
        orow[col0] = ga0 * (xo0[v] - mu) * rs + bb0 + b2f(lh0[row * 128 + col0]);
        orow[col1] = ga1 * (xo1[v] - mu) * rs + bb1 + b2f(lh0[row * 128 + col1]);
    }
}

extern "C" void kernel_launch(void* const* d_in, const int* in_sizes, int n_in,
                              void* d_out, int out_size, void* d_ws, size_t ws_size,
                              hipStream_t stream) {
    const float* f_atoms = (const float*)d_in[0];
    const float* f_bonds = (const float*)d_in[1];
    const int* a2a = (const int*)d_in[2];
    const int* a2b = (const int*)d_in[3];
    const float* W_i = (const float*)d_in[4];
    const float* b_i = (const float*)d_in[5];
    const float* ln1g = (const float*)d_in[6];
    const float* ln1b = (const float*)d_in[7];
    const float* Whq = (const float*)d_in[8];
    const float* bhq = (const float*)d_in[9];
    const float* Whk = (const float*)d_in[10];
    const float* bhk = (const float*)d_in[11];
    const float* Whv = (const float*)d_in[12];
    const float* bhv = (const float*)d_in[13];
    const float* Wo = (const float*)d_in[14];
    const float* bo = (const float*)d_in[15];
    const float* ln2g = (const float*)d_in[16];
    const float* ln2b = (const float*)d_in[17];
    float* out = (float*)d_out;

    char* ws = (char*)d_ws;
    u16* h0w = (u16*)(ws + 0);                 //  51,200,000 B
    u16* msgw = (u16*)(ws + 51200000);         // 128,000,000 B
    u16* wallw = (u16*)(ws + 179200000);       //     491,520 B
    u16* wow = (u16*)(ws + 179691520);         //      65,536 B
    u16* wiw = (u16*)(ws + 179757056);         //      40,960 B

    hipFuncSetAttribute(reinterpret_cast<const void*>(k_fused),
                        hipFuncAttributeMaxDynamicSharedMemorySize, SMEM_FUSED);

    k_wprep<<<1168, 256, 0, stream>>>(Whq, Whk, Whv, Wo, W_i, wallw, wow, wiw);
    k_h0<<<3125, 256, H0_SMEM, stream>>>(f_atoms, wiw, b_i, ln1g, ln1b, h0w);
    k_msg_h0<<<14844, 256, 0, stream>>>(h0w, a2a, msgw);
    k_msg_bond<<<16407, 256, 0, stream>>>(f_bonds, a2b, msgw);
    k_fused<<<3125, 1024, SMEM_FUSED, stream>>>(msgw, h0w, wallw, wow,
                                                bhq, bhk, bhv, bo, ln2g, ln2b, out);
}

// Round 3
// 575.672 us; speedup vs baseline: 1.2450x; 1.2217x over previous
//
#include <hip/hip_runtime.h>

typedef unsigned short u16;
typedef unsigned int u32;
typedef __attribute__((ext_vector_type(8))) short s8v;
typedef __attribute__((ext_vector_type(4))) float f4v;
typedef __attribute__((ext_vector_type(2))) float f2v;

#define NATOMS 200000
#define NBONDS 400000

// ---------- bf16 helpers ----------
__device__ __forceinline__ float b2f(u32 u) {
    union { u32 i; float f; } v; v.i = u << 16; return v.f;
}
__device__ __forceinline__ u16 f2b(float f) {
    union { float f; u32 i; } v; v.f = f;
    u32 r = v.i + 0x7fffu + ((v.i >> 16) & 1u);
    return (u16)(r >> 16);
}
__device__ __forceinline__ uint4 pack8(const float* f) {
    uint4 o;
    o.x = (u32)f2b(f[0]) | ((u32)f2b(f[1]) << 16);
    o.y = (u32)f2b(f[2]) | ((u32)f2b(f[3]) << 16);
    o.z = (u32)f2b(f[4]) | ((u32)f2b(f[5]) << 16);
    o.w = (u32)f2b(f[6]) | ((u32)f2b(f[7]) << 16);
    return o;
}
__device__ __forceinline__ void acc8(uint4 u, float* a) {
    a[0] += b2f(u.x & 0xffffu); a[1] += b2f(u.x >> 16);
    a[2] += b2f(u.y & 0xffffu); a[3] += b2f(u.y >> 16);
    a[4] += b2f(u.z & 0xffffu); a[5] += b2f(u.z >> 16);
    a[6] += b2f(u.w & 0xffffu); a[7] += b2f(u.w >> 16);
}

// ---------- weight prep ----------
// wallw: [10 ks][768 n'][32 kk]; n' = (h>>3)*48 + branch*16 + head*8 + (h&7)
// wow:   [8][128][32]   (K=256)
// wiw:   [5][128][32]   (K=160 pad of 151)
__global__ void k_wprep(const float* __restrict__ Whq, const float* __restrict__ Whk,
                        const float* __restrict__ Whv, const float* __restrict__ Wo,
                        const float* __restrict__ Wi,
                        u16* __restrict__ wallw, u16* __restrict__ wow, u16* __restrict__ wiw) {
    int t = blockIdx.x * 256 + threadIdx.x;
    if (t < 245760) {
        int ks = t / 24576, rem = t % 24576;
        int n = rem >> 5, kk = rem & 31;
        int k = ks * 32 + kk;
        int hg = n / 48, r48 = n % 48;
        int branch = r48 >> 4, r16i = r48 & 15;
        int head = r16i >> 3, h = hg * 8 + (r16i & 7);
        const float* Wp = (branch == 0) ? Whq : ((branch == 1) ? Whk : Whv);
        float val = (k < 293) ? Wp[(head * 293 + k) * 128 + h] : 0.f;
        wallw[t] = f2b(val);
    } else if (t < 278528) {
        int u = t - 245760;
        int ks = u >> 12, n = (u >> 5) & 127, kk = u & 31;
        int k = ks * 32 + kk;
        wow[u] = f2b(Wo[k * 128 + n]);
    } else if (t < 299008) {
        int u = t - 278528;
        int ks = u >> 12, n = (u >> 5) & 127, kk = u & 31;
        int k = ks * 32 + kk;
        wiw[u] = (k < 151) ? f2b(Wi[k * 128 + n]) : (u16)0;
    }
}

// ---------- f_bonds -> bf16 table [NBONDS][168] (165 + 3 zero pad) ----------
__global__ void k_bond16(const float* __restrict__ fb, u16* __restrict__ fbw) {
    int t = blockIdx.x * 256 + threadIdx.x;
    if (t >= NBONDS * 21) return;
    u32 b = (u32)t / 21u, c = (u32)t % 21u;
    const float* src = fb + (size_t)b * 165 + c * 8;
    float a[8];
    #pragma unroll
    for (int q = 0; q < 8; q++) a[q] = ((int)(c * 8 + q) < 165) ? src[q] : 0.f;
    *(uint4*)&fbw[(size_t)b * 168 + c * 8] = pack8(a);
}

// ---------- h0 = LN(relu(f_atoms @ W_i + b_i)) -> bf16 ----------
#define H0_SMEM (64 * 168 * 2 + 64 * 132 * 4)
__global__ __launch_bounds__(256) void k_h0(
    const float* __restrict__ fa, const u16* __restrict__ wiw,
    const float* __restrict__ bi, const float* __restrict__ g1, const float* __restrict__ b1,
    u16* __restrict__ h0w) {
    extern __shared__ char smem[];
    u16* la = (u16*)smem;                 // [64][168]
    float* lo = (float*)(smem + 21504);   // [64][132]
    const int tid = threadIdx.x;
    const size_t abase = (size_t)blockIdx.x * 64;

    for (int i = tid; i < 64 * 151; i += 256) {
        int r = i / 151, c = i - r * 151;
        la[r * 168 + c] = f2b(fa[(abase + r) * 151 + c]);
    }
    for (int i = tid; i < 64 * 17; i += 256) {
        int r = i / 17, c = i - r * 17;
        la[r * 168 + 151 + c] = 0;
    }
    __syncthreads();

    const int w = tid >> 6, l = tid & 63;
    const int r16 = l & 15, kq = l >> 4;
    f4v acc[4][2];
    #pragma unroll
    for (int m = 0; m < 4; m++)
        #pragma unroll
        for (int c = 0; c < 2; c++)
            #pragma unroll
            for (int v = 0; v < 4; v++) acc[m][c][v] = 0.f;

    #pragma unroll
    for (int ks = 0; ks < 5; ++ks) {
        s8v af[4];
        #pragma unroll
        for (int m = 0; m < 4; m++)
            af[m] = *(const s8v*)&la[(m * 16 + r16) * 168 + ks * 32 + kq * 8];
        #pragma unroll
        for (int c = 0; c < 2; c++) {
            int n = w * 32 + c * 16 + r16;
            s8v bf = *(const s8v*)&wiw[ks * 4096 + n * 32 + kq * 8];
            #pragma unroll
            for (int m = 0; m < 4; m++)
                acc[m][c] = __builtin_amdgcn_mfma_f32_16x16x32_bf16(af[m], bf, acc[m][c], 0, 0, 0);
        }
    }
    #pragma unroll
    for (int c = 0; c < 2; c++) {
        int col = w * 32 + c * 16 + r16;
        float bias = bi[col];
        #pragma unroll
        for (int m = 0; m < 4; m++) {
            #pragma unroll
            for (int v = 0; v < 4; v++) {
                int row = m * 16 + kq * 4 + v;
                lo[row * 132 + col] = fmaxf(acc[m][c][v] + bias, 0.f);
            }
        }
    }
    __syncthreads();

    const int ga = tid >> 2, sb = tid & 3;
    float vals[32], s = 0.f, s2 = 0.f;
    #pragma unroll
    for (int j = 0; j < 32; j++) {
        float v = lo[ga * 132 + sb + 4 * j];
        vals[j] = v; s += v; s2 += v * v;
    }
    s += __shfl_xor(s, 1); s += __shfl_xor(s, 2);
    s2 += __shfl_xor(s2, 1); s2 += __shfl_xor(s2, 2);
    float mu = s * (1.f / 128.f), var = s2 * (1.f / 128.f) - mu * mu;
    float rs = rsqrtf(var + 1e-5f);
    u16* orow = h0w + (abase + ga) * 128;
    #pragma unroll
    for (int j = 0; j < 32; j++) {
        int col = sb + 4 * j;
        orow[col] = f2b(g1[col] * (vals[j] - mu) * rs + b1[col]);
    }
}

// ---------- fused: gather-stage msg + QKV proj + attention + W_o + LN2 + residual ----------
// 64 atoms/block, 1024 threads (16 waves), 2 blocks/CU.
// LDS: lmsg [64][320] bf16 XOR-swizzled @0 (40960), GEMM phase only.
// After GEMM: sco2 f32 [16][64][4] @0 (16K) | lx bf16 [64][264] @16384 (33792)
//             attn f32 [64][4] @50176 (1K)  | pp f32 [64][8] @51200 (2K)
#define SMEM_FUSED 53248
__global__ __launch_bounds__(1024) void k_fused(
    const u16* __restrict__ h0w, const u16* __restrict__ fbw,
    const int* __restrict__ a2a, const int* __restrict__ a2b,
    const u16* __restrict__ wallw, const u16* __restrict__ wow,
    const float* __restrict__ bhq, const float* __restrict__ bhk, const float* __restrict__ bhv,
    const float* __restrict__ bo, const float* __restrict__ g2, const float* __restrict__ b2,
    float* __restrict__ out) {
    extern __shared__ char smem[];
    float* sco2 = (float*)smem;             // post-GEMM overlay
    u16* lx = (u16*)(smem + 16384);
    float* attn = (float*)(smem + 50176);
    float* pp = (float*)(smem + 51200);

    const int tid = threadIdx.x;
    const size_t abase = (size_t)blockIdx.x * 64;
    const int w = tid >> 6, l = tid & 63;
    const int r16 = l & 15, kq = l >> 4;
    const u32 xmask = (u32)((r16 & 7) << 4);

    // B-frag prefetch for first K-step (L2-resident wallw)
    const u16* bp = wallw + (size_t)(w * 48 + r16) * 32 + kq * 8;
    s8v bfA0 = *(const s8v*)&bp[0];
    s8v bfA1 = *(const s8v*)&bp[512];
    s8v bfA2 = *(const s8v*)&bp[1024];

    // gather-stage msg tile directly into swizzled LDS:
    // cols 0..127 = sum_j h0[a2a], 128..295 = sum_j fbw[a2b] (incl pad zeros), 296..319 = 0
    #pragma unroll
    for (int ii = 0; ii < 3; ++ii) {
        int i = tid + ii * 1024;
        if (i < 2560) {
            int r = i / 40, c = i - r * 40;
            uint4 val;
            if (c < 37) {
                float a[8] = {0, 0, 0, 0, 0, 0, 0, 0};
                if (c < 16) {
                    const int* na = a2a + (abase + r) * 6;
                    #pragma unroll
                    for (int j = 0; j < 6; j++)
                        acc8(*(const uint4*)&h0w[(size_t)(u32)na[j] * 128 + c * 8], a);
                } else {
                    const int* nb = a2b + (abase + r) * 6;
                    #pragma unroll
                    for (int j = 0; j < 6; j++)
                        acc8(*(const uint4*)&fbw[(size_t)(u32)nb[j] * 168 + (c - 16) * 8], a);
                }
                val = pack8(a);
            } else {
                val = (uint4){0, 0, 0, 0};
            }
            *(uint4*)(smem + (((u32)(r * 640 + c * 16)) ^ ((u32)((r & 7) << 4)))) = val;
        }
    }
    __syncthreads();  // B1: msg tile ready

    f4v acc[4][3];
    #pragma unroll
    for (int m = 0; m < 4; m++)
        #pragma unroll
        for (int c = 0; c < 3; c++)
            #pragma unroll
            for (int v = 0; v < 4; v++) acc[m][c][v] = 0.f;

    s8v bfB0, bfB1, bfB2;
    // K-loop: 10 steps, A from swizzled LDS, B double-buffered from L2, no barriers.
    #pragma unroll
    for (int kp = 0; kp < 5; ++kp) {
        {   // even step uses bfA, prefetch bfB
            const int ks = 2 * kp;
            const u16* nb = bp + (size_t)(ks + 1) * 24576;
            bfB0 = *(const s8v*)&nb[0];
            bfB1 = *(const s8v*)&nb[512];
            bfB2 = *(const s8v*)&nb[1024];
            #pragma unroll
            for (int m = 0; m < 4; m++) {
                s8v af = *(const s8v*)(smem +
                    (((u32)((m * 16 + r16) * 640 + ks * 64 + kq * 16)) ^ xmask));
                acc[m][0] = __builtin_amdgcn_mfma_f32_16x16x32_bf16(af, bfA0, acc[m][0], 0, 0, 0);
                acc[m][1] = __builtin_amdgcn_mfma_f32_16x16x32_bf16(af, bfA1, acc[m][1], 0, 0, 0);
                acc[m][2] = __builtin_amdgcn_mfma_f32_16x16x32_bf16(af, bfA2, acc[m][2], 0, 0, 0);
            }
        }
        {   // odd step uses bfB, prefetch bfA
            const int ks = 2 * kp + 1;
            if (kp < 4) {
                const u16* nb = bp + (size_t)(ks + 1) * 24576;
                bfA0 = *(const s8v*)&nb[0];
                bfA1 = *(const s8v*)&nb[512];
                bfA2 = *(const s8v*)&nb[1024];
            }
            #pragma unroll
            for (int m = 0; m < 4; m++) {
                s8v af = *(const s8v*)(smem +
                    (((u32)((m * 16 + r16) * 640 + ks * 64 + kq * 16)) ^ xmask));
                acc[m][0] = __builtin_amdgcn_mfma_f32_16x16x32_bf16(af, bfB0, acc[m][0], 0, 0, 0);
                acc[m][1] = __builtin_amdgcn_mfma_f32_16x16x32_bf16(af, bfB1, acc[m][1], 0, 0, 0);
                acc[m][2] = __builtin_amdgcn_mfma_f32_16x16x32_bf16(af, bfB2, acc[m][2], 0, 0, 0);
            }
        }
    }

    // h0 for bias-add: 16 scalar L2 loads (block's own rows, L1/L2 resident)
    const int head = r16 >> 3;
    const int h = w * 8 + (r16 & 7);
    float h0r[4][4];
    #pragma unroll
    for (int m = 0; m < 4; m++)
        #pragma unroll
        for (int v = 0; v < 4; v++)
            h0r[m][v] = b2f(h0w[(abase + m * 16 + kq * 4 + v) * 128 + h]);
    const float bq = bhq[head * 128 + h];
    const float bk = bhk[head * 128 + h];
    const float bv = bhv[head * 128 + h];

    __syncthreads();  // B2: all lmsg reads done; sco2 overlay writable

    // QKV relu + per-head score partials; reduce over in-wave h (xor 1,2,4),
    // cross-head product via one xor8; cross-wave + head-combine deferred to sco2.
    #pragma unroll
    for (int m = 0; m < 4; m++) {
        #pragma unroll
        for (int v = 0; v < 4; v++) {
            int row = m * 16 + kq * 4 + v;
            float q  = fmaxf(acc[m][0][v] + h0r[m][v] + bq, 0.f);
            float kk = fmaxf(acc[m][1][v] + h0r[m][v] + bk, 0.f);
            float vv = fmaxf(acc[m][2][v] + h0r[m][v] + bv, 0.f);
            acc[m][2][v] = vv;  // keep relu'd V
            float kx = __shfl_xor(kk, 8);
            float pA = q * kk;   // q_head . k_head partial
            float pB = q * kx;   // q_head . k_other partial
            pA += __shfl_xor(pA, 1); pA += __shfl_xor(pA, 2); pA += __shfl_xor(pA, 4);
            pB += __shfl_xor(pB, 1); pB += __shfl_xor(pB, 2); pB += __shfl_xor(pB, 4);
            if ((r16 & 7) == ((m * 4 + v) & 7)) {
                f2v pr; pr[0] = pA; pr[1] = pB;
                *(f2v*)&sco2[(w * 64 + row) * 4 + head * 2] = pr;
            }
        }
    }
    __syncthreads();  // B3

    // softmax over heads: 128 threads, one per (atom, query-head)
    if (tid < 128) {
        int atom = tid >> 1, qh = tid & 1;
        float ss = 0.f, sx = 0.f;
        #pragma unroll
        for (int ww = 0; ww < 16; ww++) {
            f2v p = *(const f2v*)&sco2[(ww * 64 + atom) * 4 + qh * 2];
            ss += p[0]; sx += p[1];
        }
        const float sc = 0.08838834764831845f;  // 1/sqrt(128)
        ss *= sc; sx *= sc;
        float mm = fmaxf(ss, sx);
        float e0 = __expf(ss - mm), e1 = __expf(sx - mm);
        float inv = 1.f / (e0 + e1);
        attn[atom * 4 + qh * 2] = e0 * inv;       // weight for own-head V
        attn[atom * 4 + qh * 2 + 1] = e1 * inv;   // weight for other-head V
    }
    __syncthreads();  // B4

    // V apply -> lx[row][head*128+h]
    #pragma unroll
    for (int m = 0; m < 4; m++) {
        #pragma unroll
        for (int v = 0; v < 4; v++) {
            int row = m * 16 + kq * 4 + v;
            f2v a = *(const f2v*)&attn[row * 4 + head * 2];
            float vv = acc[m][2][v];
            float vx = __shfl_xor(vv, 8);
            lx[row * 264 + head * 128 + h] = f2b(a[0] * vv + a[1] * vx);
        }
    }
    __syncthreads();  // B5

    // ---- x @ W_o (K=256), B frags straight from L2 ----
    const int mb = w >> 2, ch = w & 3;
    f4v oa0, oa1;
    #pragma unroll
    for (int v = 0; v < 4; v++) { oa0[v] = 0.f; oa1[v] = 0.f; }
    const u16* xp = lx + (mb * 16 + r16) * 264 + kq * 8;
    const u16* wp2 = wow + (ch * 32 + r16) * 32 + kq * 8;
    #pragma unroll
    for (int ks = 0; ks < 8; ks++) {
        s8v a = *(const s8v*)&xp[ks * 32];
        s8v b0 = *(const s8v*)&wp2[ks * 4096];
        s8v b1 = *(const s8v*)&wp2[ks * 4096 + 512];
        oa0 = __builtin_amdgcn_mfma_f32_16x16x32_bf16(a, b0, oa0, 0, 0, 0);
        oa1 = __builtin_amdgcn_mfma_f32_16x16x32_bf16(a, b1, oa1, 0, 0, 0);
    }

    // ---- epilogue: LN2 via cross-wave partial sums, residual from global h0 ----
    const int col0 = ch * 32 + r16, col1 = col0 + 16;
    const float bo0 = bo[col0], bo1 = bo[col1];
    float xo0[4], xo1[4], sv[4], s2v[4];
    #pragma unroll
    for (int v = 0; v < 4; v++) {
        xo0[v] = oa0[v] + bo0;
        xo1[v] = oa1[v] + bo1;
        float s = xo0[v] + xo1[v];
        float s2 = xo0[v] * xo0[v] + xo1[v] * xo1[v];
        s += __shfl_xor(s, 1); s += __shfl_xor(s, 2);
        s += __shfl_xor(s, 4); s += __shfl_xor(s, 8);
        s2 += __shfl_xor(s2, 1); s2 += __shfl_xor(s2, 2);
        s2 += __shfl_xor(s2, 4); s2 += __shfl_xor(s2, 8);
        sv[v] = s; s2v[v] = s2;
    }
    if (r16 == 0) {
        #pragma unroll
        for (int v = 0; v < 4; v++) {
            int row = mb * 16 + kq * 4 + v;
            pp[row * 8 + ch * 2] = sv[v];
            pp[row * 8 + ch * 2 + 1] = s2v[v];
        }
    }
    __syncthreads();  // B6

    const float ga0 = g2[col0], ga1 = g2[col1];
    const float bb0 = b2[col0], bb1 = b2[col1];
    #pragma unroll
    for (int v = 0; v < 4; v++) {
        int row = mb * 16 + kq * 4 + v;
        f4v p0 = *(f4v*)&pp[row * 8];
        f4v p1 = *(f4v*)&pp[row * 8 + 4];
        float ssum = p0[0] + p0[2] + p1[0] + p1[2];
        float s2sum = p0[1] + p0[3] + p1[1] + p1[3];
        float mu = ssum * (1.f / 128.f);
        float var = s2sum * (1.f / 128.f) - mu * mu;
        float rs = rsqrtf(var + 1e-5f);
        float* orow = out + (abase + row) * 128;
        orow[col0] = ga0 * (xo0[v] - mu) * rs + bb0 + b2f(h0w[(abase + row) * 128 + col0]);
        orow[col1] = ga1 * (xo1[v] - mu) * rs + bb1 + b2f(h0w[(abase + row) * 128 + col1]);
    }
}

extern "C" void kernel_launch(void* const* d_in, const int* in_sizes, int n_in,
                              void* d_out, int out_size, void* d_ws, size_t ws_size,
                              hipStream_t stream) {
    const float* f_atoms = (const float*)d_in[0];
    const float* f_bonds = (const float*)d_in[1];
    const int* a2a = (const int*)d_in[2];
    const int* a2b = (const int*)d_in[3];
    const float* W_i = (const float*)d_in[4];
    const float* b_i = (const float*)d_in[5];
    const float* ln1g = (const float*)d_in[6];
    const float* ln1b = (const float*)d_in[7];
    const float* Whq = (const float*)d_in[8];
    const float* bhq = (const float*)d_in[9];
    const float* Whk = (const float*)d_in[10];
    const float* bhk = (const float*)d_in[11];
    const float* Whv = (const float*)d_in[12];
    const float* bhv = (const float*)d_in[13];
    const float* Wo = (const float*)d_in[14];
    const float* bo = (const float*)d_in[15];
    const float* ln2g = (const float*)d_in[16];
    const float* ln2b = (const float*)d_in[17];
    float* out = (float*)d_out;

    char* ws = (char*)d_ws;
    u16* h0w = (u16*)(ws + 0);                  //  51,200,000 B
    u16* fbw = (u16*)(ws + 51200000);           // 134,400,000 B
    u16* wallw = (u16*)(ws + 185600000);        //     491,520 B
    u16* wow = (u16*)(ws + 186091520);          //      65,536 B
    u16* wiw = (u16*)(ws + 186157056);          //      40,960 B  (total ~186.2 MB)

    hipFuncSetAttribute(reinterpret_cast<const void*>(k_fused),
                        hipFuncAttributeMaxDynamicSharedMemorySize, SMEM_FUSED);

    k_wprep<<<1168, 256, 0, stream>>>(Whq, Whk, Whv, Wo, W_i, wallw, wow, wiw);
    k_bond16<<<32813, 256, 0, stream>>>(f_bonds, fbw);
    k_h0<<<3125, 256, H0_SMEM, stream>>>(f_atoms, wiw, b_i, ln1g, ln1b, h0w);
    k_fused<<<3125, 1024, SMEM_FUSED, stream>>>(h0w, fbw, a2a, a2b, wallw, wow,
                                                bhq, bhk, bhv, bo, ln2g, ln2b, out);
}